// Round 7
// baseline (457.319 us; speedup 1.0000x reference)
//
#include <hip/hip_runtime.h>
#include <math.h>

#define NU   16384
#define NI   4096
#define DDIM 64
#define BB   2048
#define GSTR8 2056   // u8 g-tile stride: 4-row offset = 2056*4 B -> hi-groups 8 banks apart

typedef unsigned short u16;
typedef unsigned char  u8;
typedef __attribute__((ext_vector_type(8))) short short8;
typedef __attribute__((ext_vector_type(4))) float f32x4;

// fp32 -> bf16 RNE (embeddings feeding MFMA)
static __device__ __forceinline__ u16 f2bf(float f) {
    union { float f; unsigned int u; } v; v.f = f;
    unsigned int u = v.u + 0x7FFFu + ((v.u >> 16) & 1u);
    return (u16)(u >> 16);
}

// rating [1,5] -> u8 [1,201]; NaN -> 0 (v_cvt_u32_f32 clamps NaN to 0).
// enc = trunc(50*r - 48.5) = round(50*(r-1)) + 1; decode gv = q*0.02 + 0.98, err <= 0.01
static __device__ __forceinline__ u8 enc_r(float r) {
    return (u8)__float2uint_rz(fmaf(r, 50.f, -48.5f));
}

// ===== k_qprep: Ubf[b][k]=bf16(E[uidx[b]][k]); qinfo[b]={ub, 1/|u|} =====
__global__ __launch_bounds__(256) void k_qprep(
    const float* __restrict__ E, const int* __restrict__ uidx,
    u16* __restrict__ Ubf, int2* __restrict__ qinfo)
{
    const int lane = threadIdx.x & 63;
    const int b = blockIdx.x * 4 + (threadIdx.x >> 6);
    const int ub = uidx[b];
    const float e = E[(size_t)ub * DDIM + lane];
    float ss = e * e;
#pragma unroll
    for (int o = 32; o > 0; o >>= 1) ss += __shfl_xor(ss, o);
    Ubf[b * DDIM + lane] = f2bf(e);
    if (lane == 0) qinfo[b] = make_int2(ub, __float_as_int(rsqrtf(ss)));
}

// ===== k_fused: block = 16-row n-tile.
// Phase A: WAVE-INDEPENDENT (zero block barriers): each wave owns 4 rows:
//   stream row (16 outstanding float4 loads), stats (ballot/popc count on SALU),
//   u8-encode -> wave-private LDS row, gather item column -> g rows.
// Phase B: 2x MFMA 16x16x32 bf16 per b-tile vs all 2048 b, epilogue from LDS,
//   per-block partials (no atomics). Exports avgAll[n].
// LDS 52.3 KB -> 3 blocks/CU (12 waves). Only 2 block barriers total. =====
__global__ __launch_bounds__(256) void k_fused(
    const float* __restrict__ R, const float* __restrict__ E,
    const int* __restrict__ iidx, const u16* __restrict__ Ubf,
    const int2* __restrict__ qinfo, float2* __restrict__ partials,
    float* __restrict__ avgAll)
{
    __shared__ u16 s_ii[BB];           // 4 KB
    __shared__ u8  wrow[4][NI];        // 16 KB (wave-private row buffers)
    __shared__ u8  g[16][GSTR8];       // 32.1 KB
    __shared__ float sAvg[16], sInv[16];

    const int tid  = threadIdx.x;
    const int lane = tid & 63;
    const int wid  = tid >> 6;
    const int n0   = blockIdx.x * 16;

    for (int t = tid; t < BB; t += 256) s_ii[t] = (u16)iidx[t];

    // embedding inv-norms: wave wid -> rows wid*4..+3
#pragma unroll
    for (int rs = 0; rs < 4; ++rs) {
        const int n = n0 + wid * 4 + rs;
        const float e = E[(size_t)n * DDIM + lane];
        float ss = e * e;
#pragma unroll
        for (int o = 32; o > 0; o >>= 1) ss += __shfl_xor(ss, o);
        if (lane == 0) sInv[wid * 4 + rs] = rsqrtf(ss);
    }
    __syncthreads();   // s_ii ready (also covers sInv before Phase B)

    // ---- Phase A: barrier-free, wave-owned rows ----
#pragma unroll 1
    for (int rs = 0; rs < 4; ++rs) {
        const int rloc = wid * 4 + rs;
        const int n = n0 + rloc;
        const float4* R4 = (const float4*)(R + (size_t)n * NI);

        float4 v[16];
#pragma unroll
        for (int j = 0; j < 16; ++j) v[j] = R4[j * 64 + lane];   // 16 outstanding

        float sum = 0.f;
        unsigned cnti = 0;          // wave-uniform count, SALU-side
#pragma unroll
        for (int j = 0; j < 16; ++j) {
            const float4 x = v[j];
            sum += (x.x == x.x ? x.x : 0.f);
            sum += (x.y == x.y ? x.y : 0.f);
            sum += (x.z == x.z ? x.z : 0.f);
            sum += (x.w == x.w ? x.w : 0.f);
            cnti += (unsigned)__popcll(__ballot(x.x == x.x));
            cnti += (unsigned)__popcll(__ballot(x.y == x.y));
            cnti += (unsigned)__popcll(__ballot(x.z == x.z));
            cnti += (unsigned)__popcll(__ballot(x.w == x.w));
            uchar4 q;
            q.x = enc_r(x.x); q.y = enc_r(x.y); q.z = enc_r(x.z); q.w = enc_r(x.w);
            *(uchar4*)&wrow[wid][(j * 64 + lane) * 4] = q;
        }
#pragma unroll
        for (int o = 32; o > 0; o >>= 1) sum += __shfl_xor(sum, o);
        if (lane == 0) {
            const float C = (float)cnti;
            const float a = (C > 0.f) ? (sum / C) : 0.f;
            sAvg[rloc] = a;
            avgAll[n] = a;
        }
        // wave-internal RAW fence: wrow writes visible to this wave's reads
        asm volatile("s_waitcnt lgkmcnt(0)" ::: "memory");

        // gather 2048 items from wave-private row -> g[rloc][:]
#pragma unroll
        for (int t = 0; t < 8; ++t) {
            const int b4 = (t * 64 + lane) * 4;
            const ushort4 ii = *(const ushort4*)&s_ii[b4];
            uchar4 q;
            q.x = wrow[wid][ii.x];
            q.y = wrow[wid][ii.y];
            q.z = wrow[wid][ii.z];
            q.w = wrow[wid][ii.w];
            *(uchar4*)&g[rloc][b4] = q;
        }
        // gather reads complete before next row overwrites wrow (reg-dep + fence next iter)
    }
    __syncthreads();   // all g + sAvg + sInv ready

    // ---- Phase B ----
    const int lo = lane & 15;
    const int hi = lane >> 4;

    short8 a[2];
#pragma unroll
    for (int kg = 0; kg < 2; ++kg) {
        const float* ep = E + (size_t)(n0 + lo) * DDIM + kg * 32 + hi * 8;
        const float4 e0 = *(const float4*)(ep);
        const float4 e1 = *(const float4*)(ep + 4);
        union { short8 v; u16 u[8]; } t;
        t.u[0] = f2bf(e0.x); t.u[1] = f2bf(e0.y); t.u[2] = f2bf(e0.z); t.u[3] = f2bf(e0.w);
        t.u[4] = f2bf(e1.x); t.u[5] = f2bf(e1.y); t.u[6] = f2bf(e1.z); t.u[7] = f2bf(e1.w);
        a[kg] = t.v;
    }
    float avr[4], ivr[4];
#pragma unroll
    for (int r = 0; r < 4; ++r) { avr[r] = sAvg[hi * 4 + r]; ivr[r] = sInv[hi * 4 + r]; }

    float2* pout = partials + (size_t)blockIdx.x * BB;

#pragma unroll 1
    for (int j = 0; j < 32; ++j) {
        const int b0 = (j * 4 + wid) * 16;
        const int2 q = qinfo[b0 + lo];
        const float inv_mu = __int_as_float(q.y);

        const short8 bf0 = *(const short8*)(Ubf + (size_t)(b0 + lo) * DDIM + hi * 8);
        const short8 bf1 = *(const short8*)(Ubf + (size_t)(b0 + lo) * DDIM + 32 + hi * 8);

        f32x4 c = {0.f, 0.f, 0.f, 0.f};
        c = __builtin_amdgcn_mfma_f32_16x16x32_bf16(a[0], bf0, c, 0, 0, 0);
        c = __builtin_amdgcn_mfma_f32_16x16x32_bf16(a[1], bf1, c, 0, 0, 0);

        float fnum = 0.f, fden = 0.f;
#pragma unroll
        for (int r = 0; r < 4; ++r) {
            const int nr = n0 + hi * 4 + r;                  // C/D row (m89 mapping)
            const u8 qg = g[hi * 4 + r][b0 + lo];
            const bool valid = (qg != 0) && (nr != q.x);
            const float gv = (float)(int)qg * 0.02f + 0.98f;
            const float s  = valid ? c[r] * (inv_mu * ivr[r]) : 0.f;
            fnum += (gv - avr[r]) * s;                       // s==0 kills invalid
            fden += fabsf(s);
        }
        fnum += __shfl_xor(fnum, 16); fden += __shfl_xor(fden, 16);
        fnum += __shfl_xor(fnum, 32); fden += __shfl_xor(fden, 32);
        if (lane < 16) pout[b0 + lane] = make_float2(fnum, fden);
    }
}

// ===== k_final: reduce partials, finalize =====
__global__ __launch_bounds__(256) void k_final(
    const float2* __restrict__ partials, const int2* __restrict__ qinfo,
    const float* __restrict__ avgAll, float* __restrict__ out)
{
    __shared__ float sn[8][32], sd[8][32];
    const int tid = threadIdx.x;
    const int bl  = tid & 31;
    const int ch  = tid >> 5;
    const int b   = blockIdx.x * 32 + bl;
    float n = 0.f, d = 0.f;
    for (int blk = ch; blk < NU / 16; blk += 8) {
        const float2 p = partials[(size_t)blk * BB + b];
        n += p.x; d += p.y;
    }
    sn[ch][bl] = n; sd[ch][bl] = d;
    __syncthreads();
    if (tid < 32) {
        float N = 0.f, D = 0.f;
#pragma unroll
        for (int c2 = 0; c2 < 8; ++c2) { N += sn[c2][tid]; D += sd[c2][tid]; }
        const int bb = blockIdx.x * 32 + tid;
        const float au = avgAll[qinfo[bb].x];
        out[bb] = (D == 0.f) ? au : (au + N / D);
    }
}

// ===== Launch =====
extern "C" void kernel_launch(void* const* d_in, const int* in_sizes, int n_in,
                              void* d_out, int out_size, void* d_ws, size_t ws_size,
                              hipStream_t stream)
{
    const float* R    = (const float*)d_in[0];
    const float* E    = (const float*)d_in[1];
    const int*   uidx = (const int*)d_in[2];
    const int*   iidx = (const int*)d_in[3];
    float* out = (float*)d_out;

    // ws carve: partials 16MiB | Ubf 256KB | qinfo 16KB | avgAll 64KB
    char* p = (char*)d_ws;
    float2* parts  = (float2*)p;  p += (size_t)(NU / 16) * BB * 8;
    u16*    Ubf    = (u16*)p;     p += (size_t)BB * DDIM * 2;
    int2*   qinfo  = (int2*)p;    p += (size_t)BB * 8;
    float*  avgAll = (float*)p;   p += (size_t)NU * 4;

    k_qprep<<<BB / 4, 256, 0, stream>>>(E, uidx, Ubf, qinfo);
    k_fused<<<NU / 16, 256, 0, stream>>>(R, E, iidx, Ubf, qinfo, parts, avgAll);
    k_final<<<BB / 32, 256, 0, stream>>>(parts, qinfo, avgAll, out);
}

// Round 8
// 444.245 us; speedup vs baseline: 1.0294x; 1.0294x over previous
//
#include <hip/hip_runtime.h>
#include <math.h>

#define NU   16384
#define NI   4096
#define DDIM 64
#define BB   2048

typedef unsigned short u16;
typedef unsigned char  u8;
typedef __attribute__((ext_vector_type(8))) short short8;
typedef __attribute__((ext_vector_type(4))) float f32x4;

// fp32 -> bf16 RNE (embeddings feeding MFMA)
static __device__ __forceinline__ u16 f2bf(float f) {
    union { float f; unsigned int u; } v; v.f = f;
    unsigned int u = v.u + 0x7FFFu + ((v.u >> 16) & 1u);
    return (u16)(u >> 16);
}

// rating [1,5] -> u8 [1,201]; NaN -> 0 (v_cvt_u32_f32 clamps NaN to 0).
// enc = trunc(50*r - 48.5); decode gv = q*0.02 + 0.98, err <= 0.01
static __device__ __forceinline__ u8 enc_r(float r) {
    return (u8)__float2uint_rz(fmaf(r, 50.f, -48.5f));
}

// ===== k_qprep: Ubf[b][k]=bf16(E[uidx[b]][k]); qinfo[b]={ub, 1/|u|} =====
__global__ __launch_bounds__(256) void k_qprep(
    const float* __restrict__ E, const int* __restrict__ uidx,
    u16* __restrict__ Ubf, int2* __restrict__ qinfo)
{
    const int lane = threadIdx.x & 63;
    const int b = blockIdx.x * 4 + (threadIdx.x >> 6);
    const int ub = uidx[b];
    const float e = E[(size_t)ub * DDIM + lane];
    float ss = e * e;
#pragma unroll
    for (int o = 32; o > 0; o >>= 1) ss += __shfl_xor(ss, o);
    Ubf[b * DDIM + lane] = f2bf(e);
    if (lane == 0) qinfo[b] = make_int2(ub, __float_as_int(rsqrtf(ss)));
}

// ===== k_stream: BW-bound pass. One row per wave-iter, 2 rows/wave.
// 20 KB LDS + VGPR<=64 (__launch_bounds__(256,8)) -> 8 blocks/CU = 32 waves/CU.
// Streams R once: stats (ballot count), u8-encode -> wave-private LDS row,
// item-gather -> dense u8 Gq[n][b] (coalesced uchar4). avgInv[n]={avg,1/|v|}. =====
__global__ __launch_bounds__(256, 8) void k_stream(
    const float* __restrict__ R, const float* __restrict__ E,
    const int* __restrict__ iidx,
    float2* __restrict__ avgInv, u8* __restrict__ Gq)
{
    __shared__ u16 s_ii[BB];        // 4 KB
    __shared__ u8  wrow[4][NI];     // 16 KB (wave-private)
    const int tid  = threadIdx.x;
    const int lane = tid & 63;
    const int wid  = tid >> 6;

    for (int t = tid; t < BB; t += 256) s_ii[t] = (u16)iidx[t];
    __syncthreads();

    const int wg = blockIdx.x * 4 + wid;
#pragma unroll 1
    for (int rr = 0; rr < 2; ++rr) {
        const int n = wg * 2 + rr;
        const float4* R4 = (const float4*)(R + (size_t)n * NI);
        const float e = E[(size_t)n * DDIM + lane];

        float sum = 0.f;
        unsigned cnti = 0;
#pragma unroll 1
        for (int h = 0; h < 2; ++h) {
            float4 v[8];
#pragma unroll
            for (int j = 0; j < 8; ++j) v[j] = R4[(h * 8 + j) * 64 + lane];
#pragma unroll
            for (int j = 0; j < 8; ++j) {
                const float4 x = v[j];
                sum += (x.x == x.x ? x.x : 0.f);
                sum += (x.y == x.y ? x.y : 0.f);
                sum += (x.z == x.z ? x.z : 0.f);
                sum += (x.w == x.w ? x.w : 0.f);
                cnti += (unsigned)__popcll(__ballot(x.x == x.x));
                cnti += (unsigned)__popcll(__ballot(x.y == x.y));
                cnti += (unsigned)__popcll(__ballot(x.z == x.z));
                cnti += (unsigned)__popcll(__ballot(x.w == x.w));
                uchar4 q;
                q.x = enc_r(x.x); q.y = enc_r(x.y); q.z = enc_r(x.z); q.w = enc_r(x.w);
                *(uchar4*)&wrow[wid][((h * 8 + j) * 64 + lane) * 4] = q;
            }
        }
        float ss = e * e;
#pragma unroll
        for (int o = 32; o > 0; o >>= 1) {
            ss  += __shfl_xor(ss, o);
            sum += __shfl_xor(sum, o);
        }
        if (lane == 0) {
            const float C = (float)cnti;
            avgInv[n] = make_float2((C > 0.f) ? (sum / C) : 0.f, rsqrtf(ss));
        }
        // wave-internal RAW fence: wrow writes -> gather reads
        asm volatile("s_waitcnt lgkmcnt(0)" ::: "memory");

        u8* Gn = Gq + (size_t)n * BB;
#pragma unroll
        for (int t = 0; t < 8; ++t) {
            const int b4 = (t * 64 + lane) * 4;
            const ushort4 ii = *(const ushort4*)&s_ii[b4];
            uchar4 q;
            q.x = wrow[wid][ii.x];
            q.y = wrow[wid][ii.y];
            q.z = wrow[wid][ii.z];
            q.w = wrow[wid][ii.w];
            *(uchar4*)&Gn[b4] = q;  // coalesced 256B/wave-iter
        }
    }
}

// ===== k_accum: LDS-free MFMA pass. Block = 16-row n-tile x all 2048 b.
// Gq rows read directly from L2/L3 (each row touched by exactly one block).
// 2x mfma_f32_16x16x32_bf16 per b-tile; per-block partials (no atomics). =====
__global__ __launch_bounds__(256) void k_accum(
    const float* __restrict__ E, const u16* __restrict__ Ubf,
    const u8* __restrict__ Gq, const float2* __restrict__ avgInv,
    const int2* __restrict__ qinfo, float2* __restrict__ partials)
{
    const int tid  = threadIdx.x;
    const int lane = tid & 63;
    const int wid  = tid >> 6;
    const int lo   = lane & 15;
    const int hi   = lane >> 4;
    const int n0   = blockIdx.x * 16;

    // A fragments (E rows n0..n0+15, K=64), bf16 on the fly
    short8 a[2];
#pragma unroll
    for (int kg = 0; kg < 2; ++kg) {
        const float* ep = E + (size_t)(n0 + lo) * DDIM + kg * 32 + hi * 8;
        const float4 e0 = *(const float4*)(ep);
        const float4 e1 = *(const float4*)(ep + 4);
        union { short8 v; u16 u[8]; } t;
        t.u[0] = f2bf(e0.x); t.u[1] = f2bf(e0.y); t.u[2] = f2bf(e0.z); t.u[3] = f2bf(e0.w);
        t.u[4] = f2bf(e1.x); t.u[5] = f2bf(e1.y); t.u[6] = f2bf(e1.z); t.u[7] = f2bf(e1.w);
        a[kg] = t.v;
    }
    float avr[4], ivr[4];
#pragma unroll
    for (int r = 0; r < 4; ++r) {
        const float2 ai = avgInv[n0 + hi * 4 + r];
        avr[r] = ai.x; ivr[r] = ai.y;
    }

    float2* pout = partials + (size_t)blockIdx.x * BB;

#pragma unroll 1
    for (int j = 0; j < 32; ++j) {
        const int b0 = (j * 4 + wid) * 16;
        const int2 q = qinfo[b0 + lo];
        const float inv_mu = __int_as_float(q.y);

        const short8 bf0 = *(const short8*)(Ubf + (size_t)(b0 + lo) * DDIM + hi * 8);
        const short8 bf1 = *(const short8*)(Ubf + (size_t)(b0 + lo) * DDIM + 32 + hi * 8);

        f32x4 c = {0.f, 0.f, 0.f, 0.f};
        c = __builtin_amdgcn_mfma_f32_16x16x32_bf16(a[0], bf0, c, 0, 0, 0);
        c = __builtin_amdgcn_mfma_f32_16x16x32_bf16(a[1], bf1, c, 0, 0, 0);

        float fnum = 0.f, fden = 0.f;
#pragma unroll
        for (int r = 0; r < 4; ++r) {
            const int nr = n0 + hi * 4 + r;                 // C/D row (m89 mapping)
            const u8 qg = Gq[(size_t)nr * BB + b0 + lo];
            const bool valid = (qg != 0) && (nr != q.x);
            const float gv = (float)(int)qg * 0.02f + 0.98f;
            const float s  = valid ? c[r] * (inv_mu * ivr[r]) : 0.f;
            fnum += (gv - avr[r]) * s;                      // s==0 kills invalid
            fden += fabsf(s);
        }
        fnum += __shfl_xor(fnum, 16); fden += __shfl_xor(fden, 16);
        fnum += __shfl_xor(fnum, 32); fden += __shfl_xor(fden, 32);
        if (lane < 16) pout[b0 + lane] = make_float2(fnum, fden);
    }
}

// ===== k_final: reduce partials over 1024 n-tile blocks, finalize =====
__global__ __launch_bounds__(256) void k_final(
    const float2* __restrict__ partials, const int2* __restrict__ qinfo,
    const float2* __restrict__ avgInv, float* __restrict__ out)
{
    __shared__ float sn[8][32], sd[8][32];
    const int tid = threadIdx.x;
    const int bl  = tid & 31;
    const int ch  = tid >> 5;
    const int b   = blockIdx.x * 32 + bl;
    float n = 0.f, d = 0.f;
    for (int blk = ch; blk < NU / 16; blk += 8) {
        const float2 p = partials[(size_t)blk * BB + b];
        n += p.x; d += p.y;
    }
    sn[ch][bl] = n; sd[ch][bl] = d;
    __syncthreads();
    if (tid < 32) {
        float N = 0.f, D = 0.f;
#pragma unroll
        for (int c2 = 0; c2 < 8; ++c2) { N += sn[c2][tid]; D += sd[c2][tid]; }
        const int bb = blockIdx.x * 32 + tid;
        const float au = avgInv[qinfo[bb].x].x;
        out[bb] = (D == 0.f) ? au : (au + N / D);
    }
}

// ===== Launch =====
extern "C" void kernel_launch(void* const* d_in, const int* in_sizes, int n_in,
                              void* d_out, int out_size, void* d_ws, size_t ws_size,
                              hipStream_t stream)
{
    const float* R    = (const float*)d_in[0];
    const float* E    = (const float*)d_in[1];
    const int*   uidx = (const int*)d_in[2];
    const int*   iidx = (const int*)d_in[3];
    float* out = (float*)d_out;

    // ws carve: partials 16MiB | Gq 32MiB | Ubf 256KB | qinfo 16KB | avgInv 128KB
    char* p = (char*)d_ws;
    float2* parts  = (float2*)p;  p += (size_t)(NU / 16) * BB * 8;
    u8*     Gq     = (u8*)p;      p += (size_t)NU * BB;
    u16*    Ubf    = (u16*)p;     p += (size_t)BB * DDIM * 2;
    int2*   qinfo  = (int2*)p;    p += (size_t)BB * 8;
    float2* avgInv = (float2*)p;  p += (size_t)NU * 8;

    k_qprep<<<BB / 4, 256, 0, stream>>>(E, uidx, Ubf, qinfo);
    k_stream<<<NU / 8, 256, 0, stream>>>(R, E, iidx, avgInv, Gq);
    k_accum<<<NU / 16, 256, 0, stream>>>(E, Ubf, Gq, avgInv, qinfo, parts);
    k_final<<<BB / 32, 256, 0, stream>>>(parts, qinfo, avgInv, out);
}

// Round 9
// 438.816 us; speedup vs baseline: 1.0422x; 1.0124x over previous
//
#include <hip/hip_runtime.h>
#include <math.h>

#define NU   16384
#define NI   4096
#define DDIM 64
#define BB   2048

typedef unsigned short u16;
typedef unsigned char  u8;
typedef __attribute__((ext_vector_type(8))) short short8;
typedef __attribute__((ext_vector_type(4))) float f32x4;

// fp32 -> bf16 RNE (embeddings feeding MFMA)
static __device__ __forceinline__ u16 f2bf(float f) {
    union { float f; unsigned int u; } v; v.f = f;
    unsigned int u = v.u + 0x7FFFu + ((v.u >> 16) & 1u);
    return (u16)(u >> 16);
}

// rating [1,5] -> u8 [1,201]; NaN -> 0 (v_cvt_u32_f32 clamps NaN to 0).
// enc = trunc(50*r - 48.5); decode gv = q*0.02 + 0.98, err <= 0.01
static __device__ __forceinline__ u8 enc_r(float r) {
    return (u8)__float2uint_rz(fmaf(r, 50.f, -48.5f));
}

// ===== k_qprep: Ubf[b][k]=bf16(E[uidx[b]][k]); qinfo[b]={ub, 1/|u|} =====
__global__ __launch_bounds__(256) void k_qprep(
    const float* __restrict__ E, const int* __restrict__ uidx,
    u16* __restrict__ Ubf, int2* __restrict__ qinfo)
{
    const int lane = threadIdx.x & 63;
    const int b = blockIdx.x * 4 + (threadIdx.x >> 6);
    const int ub = uidx[b];
    const float e = E[(size_t)ub * DDIM + lane];
    float ss = e * e;
#pragma unroll
    for (int o = 32; o > 0; o >>= 1) ss += __shfl_xor(ss, o);
    Ubf[b * DDIM + lane] = f2bf(e);
    if (lane == 0) qinfo[b] = make_int2(ub, __float_as_int(rsqrtf(ss)));
}

// ===== k_stream: latency-proof streaming pass.
// __launch_bounds__(256,4): 128-VGPR budget (no spills), 4 blocks/CU = 16 waves/CU.
// Each wave owns 2 rows; explicit 2-deep register pipeline (X/Y = 8 float4 each,
// one full batch always in flight) + per-wave double-buffered LDS row so the
// row-0 gather overlaps row-1 loads. Writes avgInv[n] and dense u8 Gq[n][b]. =====
__global__ __launch_bounds__(256, 4) void k_stream(
    const float* __restrict__ R, const float* __restrict__ E,
    const int* __restrict__ iidx,
    float2* __restrict__ avgInv, u8* __restrict__ Gq)
{
    __shared__ u16 s_ii[BB];           // 4 KB
    __shared__ u8  wrow[4][2][NI];     // 32 KB (wave-private, double-buffered)
    const int tid  = threadIdx.x;
    const int lane = tid & 63;
    const int wid  = tid >> 6;

    for (int t = tid; t < BB; t += 256) s_ii[t] = (u16)iidx[t];
    __syncthreads();

    const int n0 = (blockIdx.x * 4 + wid) * 2;
    const float4* R0 = (const float4*)(R + (size_t)n0 * NI);
    const float4* R1 = (const float4*)(R + (size_t)(n0 + 1) * NI);

    // embedding-norm loads issued early (consumed at the reduces)
    const float e0 = E[(size_t)n0 * DDIM + lane];
    const float e1 = E[(size_t)(n0 + 1) * DDIM + lane];

    float4 X[8], Y[8];
#pragma unroll
    for (int j = 0; j < 8; ++j) X[j] = R0[j * 64 + lane];        // b0 in flight
#pragma unroll
    for (int j = 0; j < 8; ++j) Y[j] = R0[(8 + j) * 64 + lane];  // b1 in flight

    float sum0 = 0.f, cnt0 = 0.f, sum1 = 0.f, cnt1 = 0.f;

    // ---- consume b0 (row0 h0), refill X <- b2 (row1 h0) ----
#pragma unroll
    for (int j = 0; j < 8; ++j) {
        const float4 x = X[j];
        if (x.x == x.x) { sum0 += x.x; cnt0 += 1.f; }
        if (x.y == x.y) { sum0 += x.y; cnt0 += 1.f; }
        if (x.z == x.z) { sum0 += x.z; cnt0 += 1.f; }
        if (x.w == x.w) { sum0 += x.w; cnt0 += 1.f; }
        uchar4 q;
        q.x = enc_r(x.x); q.y = enc_r(x.y); q.z = enc_r(x.z); q.w = enc_r(x.w);
        *(uchar4*)&wrow[wid][0][(j * 64 + lane) * 4] = q;
        X[j] = R1[j * 64 + lane];
    }
    // ---- consume b1 (row0 h1), refill Y <- b3 (row1 h1) ----
#pragma unroll
    for (int j = 0; j < 8; ++j) {
        const float4 x = Y[j];
        if (x.x == x.x) { sum0 += x.x; cnt0 += 1.f; }
        if (x.y == x.y) { sum0 += x.y; cnt0 += 1.f; }
        if (x.z == x.z) { sum0 += x.z; cnt0 += 1.f; }
        if (x.w == x.w) { sum0 += x.w; cnt0 += 1.f; }
        uchar4 q;
        q.x = enc_r(x.x); q.y = enc_r(x.y); q.z = enc_r(x.z); q.w = enc_r(x.w);
        *(uchar4*)&wrow[wid][0][((8 + j) * 64 + lane) * 4] = q;
        Y[j] = R1[(8 + j) * 64 + lane];
    }
    // row0 stats reduce + store
    {
        float ss = e0 * e0, s = sum0, c = cnt0;
#pragma unroll
        for (int o = 32; o > 0; o >>= 1) {
            ss += __shfl_xor(ss, o); s += __shfl_xor(s, o); c += __shfl_xor(c, o);
        }
        if (lane == 0) avgInv[n0] = make_float2((c > 0.f) ? (s / c) : 0.f, rsqrtf(ss));
    }
    // row0 gather (wrow[wid][0] complete; fence write->read within wave)
    asm volatile("s_waitcnt lgkmcnt(0)" ::: "memory");
    {
        u8* Gn = Gq + (size_t)n0 * BB;
#pragma unroll
        for (int t8 = 0; t8 < 8; ++t8) {
            const int b4 = (t8 * 64 + lane) * 4;
            const ushort4 ii = *(const ushort4*)&s_ii[b4];
            uchar4 q;
            q.x = wrow[wid][0][ii.x];
            q.y = wrow[wid][0][ii.y];
            q.z = wrow[wid][0][ii.z];
            q.w = wrow[wid][0][ii.w];
            *(uchar4*)&Gn[b4] = q;
        }
    }
    // ---- consume b2 (row1 h0) ----
#pragma unroll
    for (int j = 0; j < 8; ++j) {
        const float4 x = X[j];
        if (x.x == x.x) { sum1 += x.x; cnt1 += 1.f; }
        if (x.y == x.y) { sum1 += x.y; cnt1 += 1.f; }
        if (x.z == x.z) { sum1 += x.z; cnt1 += 1.f; }
        if (x.w == x.w) { sum1 += x.w; cnt1 += 1.f; }
        uchar4 q;
        q.x = enc_r(x.x); q.y = enc_r(x.y); q.z = enc_r(x.z); q.w = enc_r(x.w);
        *(uchar4*)&wrow[wid][1][(j * 64 + lane) * 4] = q;
    }
    // ---- consume b3 (row1 h1) ----
#pragma unroll
    for (int j = 0; j < 8; ++j) {
        const float4 x = Y[j];
        if (x.x == x.x) { sum1 += x.x; cnt1 += 1.f; }
        if (x.y == x.y) { sum1 += x.y; cnt1 += 1.f; }
        if (x.z == x.z) { sum1 += x.z; cnt1 += 1.f; }
        if (x.w == x.w) { sum1 += x.w; cnt1 += 1.f; }
        uchar4 q;
        q.x = enc_r(x.x); q.y = enc_r(x.y); q.z = enc_r(x.z); q.w = enc_r(x.w);
        *(uchar4*)&wrow[wid][1][((8 + j) * 64 + lane) * 4] = q;
    }
    // row1 stats reduce + store
    {
        float ss = e1 * e1, s = sum1, c = cnt1;
#pragma unroll
        for (int o = 32; o > 0; o >>= 1) {
            ss += __shfl_xor(ss, o); s += __shfl_xor(s, o); c += __shfl_xor(c, o);
        }
        if (lane == 0) avgInv[n0 + 1] = make_float2((c > 0.f) ? (s / c) : 0.f, rsqrtf(ss));
    }
    // row1 gather
    asm volatile("s_waitcnt lgkmcnt(0)" ::: "memory");
    {
        u8* Gn = Gq + (size_t)(n0 + 1) * BB;
#pragma unroll
        for (int t8 = 0; t8 < 8; ++t8) {
            const int b4 = (t8 * 64 + lane) * 4;
            const ushort4 ii = *(const ushort4*)&s_ii[b4];
            uchar4 q;
            q.x = wrow[wid][1][ii.x];
            q.y = wrow[wid][1][ii.y];
            q.z = wrow[wid][1][ii.z];
            q.w = wrow[wid][1][ii.w];
            *(uchar4*)&Gn[b4] = q;
        }
    }
}

// ===== k_accum: LDS-free MFMA pass. Block = 16-row n-tile x all 2048 b.
// Gq rows read directly from L2/L3 (each row touched by exactly one block). =====
__global__ __launch_bounds__(256) void k_accum(
    const float* __restrict__ E, const u16* __restrict__ Ubf,
    const u8* __restrict__ Gq, const float2* __restrict__ avgInv,
    const int2* __restrict__ qinfo, float2* __restrict__ partials)
{
    const int tid  = threadIdx.x;
    const int lane = tid & 63;
    const int wid  = tid >> 6;
    const int lo   = lane & 15;
    const int hi   = lane >> 4;
    const int n0   = blockIdx.x * 16;

    short8 a[2];
#pragma unroll
    for (int kg = 0; kg < 2; ++kg) {
        const float* ep = E + (size_t)(n0 + lo) * DDIM + kg * 32 + hi * 8;
        const float4 e0 = *(const float4*)(ep);
        const float4 e1 = *(const float4*)(ep + 4);
        union { short8 v; u16 u[8]; } t;
        t.u[0] = f2bf(e0.x); t.u[1] = f2bf(e0.y); t.u[2] = f2bf(e0.z); t.u[3] = f2bf(e0.w);
        t.u[4] = f2bf(e1.x); t.u[5] = f2bf(e1.y); t.u[6] = f2bf(e1.z); t.u[7] = f2bf(e1.w);
        a[kg] = t.v;
    }
    float avr[4], ivr[4];
#pragma unroll
    for (int r = 0; r < 4; ++r) {
        const float2 ai = avgInv[n0 + hi * 4 + r];
        avr[r] = ai.x; ivr[r] = ai.y;
    }

    float2* pout = partials + (size_t)blockIdx.x * BB;

#pragma unroll 1
    for (int j = 0; j < 32; ++j) {
        const int b0 = (j * 4 + wid) * 16;
        const int2 q = qinfo[b0 + lo];
        const float inv_mu = __int_as_float(q.y);

        const short8 bf0 = *(const short8*)(Ubf + (size_t)(b0 + lo) * DDIM + hi * 8);
        const short8 bf1 = *(const short8*)(Ubf + (size_t)(b0 + lo) * DDIM + 32 + hi * 8);

        f32x4 c = {0.f, 0.f, 0.f, 0.f};
        c = __builtin_amdgcn_mfma_f32_16x16x32_bf16(a[0], bf0, c, 0, 0, 0);
        c = __builtin_amdgcn_mfma_f32_16x16x32_bf16(a[1], bf1, c, 0, 0, 0);

        float fnum = 0.f, fden = 0.f;
#pragma unroll
        for (int r = 0; r < 4; ++r) {
            const int nr = n0 + hi * 4 + r;                 // C/D row (m89 mapping)
            const u8 qg = Gq[(size_t)nr * BB + b0 + lo];
            const bool valid = (qg != 0) && (nr != q.x);
            const float gv = (float)(int)qg * 0.02f + 0.98f;
            const float s  = valid ? c[r] * (inv_mu * ivr[r]) : 0.f;
            fnum += (gv - avr[r]) * s;                      // s==0 kills invalid
            fden += fabsf(s);
        }
        fnum += __shfl_xor(fnum, 16); fden += __shfl_xor(fden, 16);
        fnum += __shfl_xor(fnum, 32); fden += __shfl_xor(fden, 32);
        if (lane < 16) pout[b0 + lane] = make_float2(fnum, fden);
    }
}

// ===== k_final: reduce partials over 1024 n-tile blocks, finalize =====
__global__ __launch_bounds__(256) void k_final(
    const float2* __restrict__ partials, const int2* __restrict__ qinfo,
    const float2* __restrict__ avgInv, float* __restrict__ out)
{
    __shared__ float sn[8][32], sd[8][32];
    const int tid = threadIdx.x;
    const int bl  = tid & 31;
    const int ch  = tid >> 5;
    const int b   = blockIdx.x * 32 + bl;
    float n = 0.f, d = 0.f;
    for (int blk = ch; blk < NU / 16; blk += 8) {
        const float2 p = partials[(size_t)blk * BB + b];
        n += p.x; d += p.y;
    }
    sn[ch][bl] = n; sd[ch][bl] = d;
    __syncthreads();
    if (tid < 32) {
        float N = 0.f, D = 0.f;
#pragma unroll
        for (int c2 = 0; c2 < 8; ++c2) { N += sn[c2][tid]; D += sd[c2][tid]; }
        const int bb = blockIdx.x * 32 + tid;
        const float au = avgInv[qinfo[bb].x].x;
        out[bb] = (D == 0.f) ? au : (au + N / D);
    }
}

// ===== Launch =====
extern "C" void kernel_launch(void* const* d_in, const int* in_sizes, int n_in,
                              void* d_out, int out_size, void* d_ws, size_t ws_size,
                              hipStream_t stream)
{
    const float* R    = (const float*)d_in[0];
    const float* E    = (const float*)d_in[1];
    const int*   uidx = (const int*)d_in[2];
    const int*   iidx = (const int*)d_in[3];
    float* out = (float*)d_out;

    // ws carve: partials 16MiB | Gq 32MiB | Ubf 256KB | qinfo 16KB | avgInv 128KB
    char* p = (char*)d_ws;
    float2* parts  = (float2*)p;  p += (size_t)(NU / 16) * BB * 8;
    u8*     Gq     = (u8*)p;      p += (size_t)NU * BB;
    u16*    Ubf    = (u16*)p;     p += (size_t)BB * DDIM * 2;
    int2*   qinfo  = (int2*)p;    p += (size_t)BB * 8;
    float2* avgInv = (float2*)p;  p += (size_t)NU * 8;

    k_qprep<<<BB / 4, 256, 0, stream>>>(E, uidx, Ubf, qinfo);
    k_stream<<<NU / 8, 256, 0, stream>>>(R, E, iidx, avgInv, Gq);
    k_accum<<<NU / 16, 256, 0, stream>>>(E, Ubf, Gq, avgInv, qinfo, parts);
    k_final<<<BB / 32, 256, 0, stream>>>(parts, qinfo, avgInv, out);
}